// Round 3
// baseline (127.663 us; speedup 1.0000x reference)
//
#include <hip/hip_runtime.h>
#include <math.h>

#define DIM   768
#define BATCH 4096
#define NQ    8
#define EPSLN 1e-5f

// ---------------------------------------------------------------------------
// Statevector layout: 9 wires, 512 amplitudes. TWO batch rows per wave.
//   amp index I = (lane << 3) | (r & 7), row = r >> 3  (r = 0..15)
//   wires 0..2  -> bits 0..2 of r (in-register)
//   wires 3..8  -> bits 0..5 of lane
// Two independent gate streams per wave fill each other's DS-latency bubbles.
// ---------------------------------------------------------------------------

__device__ __forceinline__ float shflx(float v, int m) { return __shfl_xor(v, m, 64); }

// RZ: diag(e^{-i t/2}, e^{+i t/2}) — never shuffles.
template<int W>
__device__ __forceinline__ void gate_rz(float (&re)[16], float (&im)[16],
                                        float c0, float s0, float c1, float s1,
                                        int lane) {
  if constexpr (W < 3) {
#pragma unroll
    for (int r = 0; r < 16; ++r) {
      const float c = (r < 8) ? c0 : c1;
      const float t = (((r >> W) & 1) ? 1.f : -1.f) * ((r < 8) ? s0 : s1);
      const float xx = re[r], yy = im[r];
      re[r] = xx * c - yy * t;
      im[r] = yy * c + xx * t;
    }
  } else {
    const float sgn = ((lane >> (W - 3)) & 1) ? 1.f : -1.f;
    const float t0 = sgn * s0, t1 = sgn * s1;
#pragma unroll
    for (int r = 0; r < 16; ++r) {
      const float c = (r < 8) ? c0 : c1;
      const float t = (r < 8) ? t0 : t1;
      const float xx = re[r], yy = im[r];
      re[r] = xx * c - yy * t;
      im[r] = yy * c + xx * t;
    }
  }
}

// RX: [[c, -i s], [-i s, c]]
template<int W>
__device__ __forceinline__ void gate_rx(float (&re)[16], float (&im)[16],
                                        float c0, float s0, float c1, float s1) {
  if constexpr (W < 3) {
#pragma unroll
    for (int r = 0; r < 16; ++r) {
      if (!((r >> W) & 1)) {
        const int r2 = r | (1 << W);
        const float c = (r < 8) ? c0 : c1;
        const float s = (r < 8) ? s0 : s1;
        const float ar = re[r], ai = im[r], br = re[r2], bi = im[r2];
        re[r]  = c * ar + s * bi;
        im[r]  = c * ai - s * br;
        re[r2] = c * br + s * ai;
        im[r2] = c * bi - s * ar;
      }
    }
  } else {
    const int mask = 1 << (W - 3);
    float ore[16], oim[16];
#pragma unroll
    for (int r = 0; r < 16; ++r) { ore[r] = shflx(re[r], mask); oim[r] = shflx(im[r], mask); }
#pragma unroll
    for (int r = 0; r < 16; ++r) {
      const float c = (r < 8) ? c0 : c1;
      const float s = (r < 8) ? s0 : s1;
      const float xx = re[r], yy = im[r];
      re[r] = c * xx + s * oim[r];
      im[r] = c * yy - s * ore[r];
    }
  }
}

// RY: [[c, -s], [s, c]]
template<int W>
__device__ __forceinline__ void gate_ry(float (&re)[16], float (&im)[16],
                                        float c0, float s0, float c1, float s1,
                                        int lane) {
  if constexpr (W < 3) {
#pragma unroll
    for (int r = 0; r < 16; ++r) {
      if (!((r >> W) & 1)) {
        const int r2 = r | (1 << W);
        const float c = (r < 8) ? c0 : c1;
        const float s = (r < 8) ? s0 : s1;
        const float ar = re[r], ai = im[r], br = re[r2], bi = im[r2];
        re[r]  = c * ar - s * br;
        im[r]  = c * ai - s * bi;
        re[r2] = s * ar + c * br;
        im[r2] = s * ai + c * bi;
      }
    }
  } else {
    const int mask = 1 << (W - 3);
    const float sgn = ((lane >> (W - 3)) & 1) ? 1.f : -1.f;
    const float t0 = sgn * s0, t1 = sgn * s1;
    float ore[16], oim[16];
#pragma unroll
    for (int r = 0; r < 16; ++r) { ore[r] = shflx(re[r], mask); oim[r] = shflx(im[r], mask); }
#pragma unroll
    for (int r = 0; r < 16; ++r) {
      const float c = (r < 8) ? c0 : c1;
      const float t = (r < 8) ? t0 : t1;
      re[r] = c * re[r] + t * ore[r];
      im[r] = c * im[r] + t * oim[r];
    }
  }
}

// CNOT(C, T)
template<int C, int T>
__device__ __forceinline__ void gate_cnot(float (&re)[16], float (&im)[16], int lane) {
  if constexpr (C < 3 && T < 3) {          // both local: register permute
#pragma unroll
    for (int r = 0; r < 16; ++r) {
      if (((r >> C) & 1) && !((r >> T) & 1)) {
        const int r2 = r | (1 << T);
        const float tr = re[r], ti = im[r];
        re[r] = re[r2]; im[r] = im[r2];
        re[r2] = tr;    im[r2] = ti;
      }
    }
  } else if constexpr (C < 3) {            // local control, lane target
    const int mask = 1 << (T - 3);
#pragma unroll
    for (int r = 0; r < 16; ++r) {
      if ((r >> C) & 1) {
        re[r] = shflx(re[r], mask);
        im[r] = shflx(im[r], mask);
      }
    }
  } else if constexpr (T < 3) {            // lane control, local target: selects
    const bool cc = (lane >> (C - 3)) & 1;
#pragma unroll
    for (int r = 0; r < 16; ++r) {
      if (!((r >> T) & 1)) {
        const int r2 = r | (1 << T);
        const float ar = re[r], ai = im[r], br = re[r2], bi = im[r2];
        re[r]  = cc ? br : ar;  im[r]  = cc ? bi : ai;
        re[r2] = cc ? ar : br;  im[r2] = cc ? ai : bi;
      }
    }
  } else {                                 // lane control, lane target
    const int mask = 1 << (T - 3);
    const bool cc = (lane >> (C - 3)) & 1;
    float ore[16], oim[16];
#pragma unroll
    for (int r = 0; r < 16; ++r) { ore[r] = shflx(re[r], mask); oim[r] = shflx(im[r], mask); }
#pragma unroll
    for (int r = 0; r < 16; ++r) {
      re[r] = cc ? ore[r] : re[r];
      im[r] = cc ? oim[r] : im[r];
    }
  }
}

// ---------------------------------------------------------------------------
__global__ void precompute_trig(const float* __restrict__ qw, float* __restrict__ cs) {
  const int i = threadIdx.x;
  if (i < 36) {
    float s, c;
    sincosf(0.5f * qw[i], &s, &c);
    cs[2 * i]     = c;
    cs[2 * i + 1] = s;
  }
}

// ---------------------------------------------------------------------------
// One wave = 2 batch rows, fully fused.
// ---------------------------------------------------------------------------
__global__ __launch_bounds__(256, 2)
void quantum_fused(const float* __restrict__ x,
                   const float* __restrict__ w_in,
                   const float* __restrict__ b_in,
                   const float* __restrict__ gamma,
                   const float* __restrict__ beta,
                   const float* __restrict__ w_out,
                   const float* __restrict__ b_out,
                   const float* __restrict__ cs,
                   float* __restrict__ out) {
  const int lane = threadIdx.x & 63;
  const int wv   = threadIdx.x >> 6;
  const int rowA = blockIdx.x * 8 + wv * 2;      // 4 waves/block, 2 rows/wave
  const int rowB = rowA + 1;

  const float4* xvA = (const float4*)(x + (size_t)rowA * DIM);
  const float4* xvB = (const float4*)(x + (size_t)rowB * DIM);

  // ---- load both x rows (kept for residual) ----
  float4 xrA[3], xrB[3];
#pragma unroll
  for (int k = 0; k < 3; ++k) { xrA[k] = xvA[lane + 64 * k]; xrB[k] = xvB[lane + 64 * k]; }

  // ---- input projection: 8 dots per row, w_in tile shared ----
  float h[16];
#pragma unroll
  for (int q = 0; q < 8; ++q) {
    const float4* wq = (const float4*)(w_in + q * DIM);
    float aA = 0.f, aB = 0.f;
#pragma unroll
    for (int k = 0; k < 3; ++k) {
      const float4 w4 = wq[lane + 64 * k];
      aA += xrA[k].x * w4.x + xrA[k].y * w4.y + xrA[k].z * w4.z + xrA[k].w * w4.w;
      aB += xrB[k].x * w4.x + xrB[k].y * w4.y + xrB[k].z * w4.z + xrB[k].w * w4.w;
    }
    h[q] = aA; h[8 + q] = aB;
  }
#pragma unroll
  for (int m = 1; m < 64; m <<= 1) {
#pragma unroll
    for (int q = 0; q < 16; ++q) h[q] += shflx(h[q], m);
  }

  // ---- bias + tanh + LayerNorm (per row) ----
  float ang[16];
#pragma unroll
  for (int rowi = 0; rowi < 2; ++rowi) {
    const int o = rowi * 8;
#pragma unroll
    for (int q = 0; q < 8; ++q) h[o + q] = tanhf(h[o + q] + b_in[q]);
    float mu = 0.f;
#pragma unroll
    for (int q = 0; q < 8; ++q) mu += h[o + q];
    mu *= 0.125f;
    float var = 0.f;
#pragma unroll
    for (int q = 0; q < 8; ++q) { const float d = h[o + q] - mu; var += d * d; }
    var *= 0.125f;
    const float inv = 1.0f / sqrtf(var + EPSLN);
#pragma unroll
    for (int q = 0; q < 8; ++q)
      ang[o + q] = (h[o + q] - mu) * inv * gamma[q] + beta[q];
  }

  // ---- circuit ----
  float re[16], im[16];
#pragma unroll
  for (int r = 0; r < 16; ++r) { re[r] = 0.f; im[r] = 0.f; }
  re[0] = (lane == 0) ? 1.f : 0.f;
  re[8] = (lane == 0) ? 1.f : 0.f;

#define ENC_I(i) { float sA, cA, sB, cB;                                       \
                   sincosf(0.5f * ang[i], &sA, &cA);                           \
                   sincosf(0.5f * ang[8 + i], &sB, &cB);                       \
                   gate_rx<i>(re, im, cA, sA, cB, sB);                         \
                   gate_rz<i>(re, im, cA, sA, cB, sB, lane); }
  ENC_I(0) ENC_I(1) ENC_I(2) ENC_I(3) ENC_I(4) ENC_I(5) ENC_I(6) ENC_I(7)
#undef ENC_I

#define L0_I(i) { const float c0 = cs[2*(i)],     s0 = cs[2*(i)+1];            \
                  const float c1 = cs[2*(9+(i))], s1 = cs[2*(9+(i))+1];        \
                  gate_rx<i>(re, im, c0, s0, c0, s0);                          \
                  gate_rz<i>(re, im, c1, s1, c1, s1, lane); }
  L0_I(0) L0_I(1) L0_I(2) L0_I(3) L0_I(4) L0_I(5) L0_I(6) L0_I(7)
#undef L0_I

#define LSTEP(l, i, j) { gate_cnot<i, j>(re, im, lane);                        \
                         const float c_ = cs[2*((l)*9+(i))];                   \
                         const float s_ = cs[2*((l)*9+(i))+1];                 \
                         gate_ry<i>(re, im, c_, s_, c_, s_, lane);             \
                         gate_rz<i>(re, im, c_, s_, c_, s_, lane); }
#define LAYER(l)                                                               \
  LSTEP(l,0,1) LSTEP(l,1,2) LSTEP(l,2,3) LSTEP(l,3,4)                          \
  LSTEP(l,4,5) LSTEP(l,5,6) LSTEP(l,6,7) LSTEP(l,7,0)                          \
  { gate_cnot<7, 8>(re, im, lane);                                             \
    gate_ry<8>(re, im, cs[2*((l)*9+8)], cs[2*((l)*9+8)+1],                     \
                        cs[2*((l)*9+8)], cs[2*((l)*9+8)+1], lane); }
  LAYER(1) LAYER(2) LAYER(3)
#undef LAYER
#undef LSTEP

  // ---- measurement ----
  float p[16];
#pragma unroll
  for (int r = 0; r < 16; ++r) p[r] = re[r] * re[r] + im[r] * im[r];
  float ptotA = 0.f, ptotB = 0.f;
#pragma unroll
  for (int r = 0; r < 8; ++r) { ptotA += p[r]; ptotB += p[8 + r]; }
  float z[16];
#pragma unroll
  for (int i = 0; i < 3; ++i) {
    float aA = 0.f, aB = 0.f;
#pragma unroll
    for (int r = 0; r < 8; ++r) {
      const float sg = ((r >> i) & 1) ? -1.f : 1.f;
      aA += sg * p[r];
      aB += sg * p[8 + r];
    }
    z[i] = aA; z[8 + i] = aB;
  }
#pragma unroll
  for (int i = 3; i < 8; ++i) {
    const float sg = ((lane >> (i - 3)) & 1) ? -1.f : 1.f;
    z[i] = sg * ptotA;
    z[8 + i] = sg * ptotB;
  }
#pragma unroll
  for (int m = 1; m < 64; m <<= 1) {
#pragma unroll
    for (int i = 0; i < 16; ++i) z[i] += shflx(z[i], m);
  }

  // ---- output projection + residual, both rows ----
#pragma unroll
  for (int rowi = 0; rowi < 2; ++rowi) {
    const int row = rowi ? rowB : rowA;
    const float4* xr = rowi ? xrB : xrA;
    const float* zz = z + rowi * 8;
    float4* ov = (float4*)(out + (size_t)row * DIM);
    const float4* bv = (const float4*)b_out;
#pragma unroll
    for (int k = 0; k < 3; ++k) {
      const int j4 = lane + 64 * k;
      const float4 b4 = bv[j4];
      const float4* wo = (const float4*)(w_out + (size_t)j4 * 32);
      const float4 r0a = wo[0], r0b = wo[1];
      const float4 r1a = wo[2], r1b = wo[3];
      const float4 r2a = wo[4], r2b = wo[5];
      const float4 r3a = wo[6], r3b = wo[7];
      float4 o;
      o.x = xr[k].x + b4.x + zz[0]*r0a.x + zz[1]*r0a.y + zz[2]*r0a.z + zz[3]*r0a.w
                          + zz[4]*r0b.x + zz[5]*r0b.y + zz[6]*r0b.z + zz[7]*r0b.w;
      o.y = xr[k].y + b4.y + zz[0]*r1a.x + zz[1]*r1a.y + zz[2]*r1a.z + zz[3]*r1a.w
                          + zz[4]*r1b.x + zz[5]*r1b.y + zz[6]*r1b.z + zz[7]*r1b.w;
      o.z = xr[k].z + b4.z + zz[0]*r2a.x + zz[1]*r2a.y + zz[2]*r2a.z + zz[3]*r2a.w
                          + zz[4]*r2b.x + zz[5]*r2b.y + zz[6]*r2b.z + zz[7]*r2b.w;
      o.w = xr[k].w + b4.w + zz[0]*r3a.x + zz[1]*r3a.y + zz[2]*r3a.z + zz[3]*r3a.w
                          + zz[4]*r3b.x + zz[5]*r3b.y + zz[6]*r3b.z + zz[7]*r3b.w;
      ov[j4] = o;
    }
  }
}

extern "C" void kernel_launch(void* const* d_in, const int* in_sizes, int n_in,
                              void* d_out, int out_size, void* d_ws, size_t ws_size,
                              hipStream_t stream) {
  const float* x     = (const float*)d_in[0];
  const float* w_in  = (const float*)d_in[1];
  const float* b_in  = (const float*)d_in[2];
  const float* gamma = (const float*)d_in[3];
  const float* beta  = (const float*)d_in[4];
  const float* q_w   = (const float*)d_in[5];
  const float* w_out = (const float*)d_in[6];
  const float* b_out = (const float*)d_in[7];
  float* outp = (float*)d_out;
  float* cs   = (float*)d_ws;   // 72 floats: (cos, sin) of q_w/2

  hipLaunchKernelGGL(precompute_trig, dim3(1), dim3(64), 0, stream, q_w, cs);
  hipLaunchKernelGGL(quantum_fused, dim3(BATCH / 8), dim3(256), 0, stream,
                     x, w_in, b_in, gamma, beta, w_out, b_out, cs, outp);
}

// Round 4
// 105.953 us; speedup vs baseline: 1.2049x; 1.2049x over previous
//
#include <hip/hip_runtime.h>
#include <math.h>

#define DIM   768
#define BATCH 4096
#define EPSLN 1e-5f

// ---------------------------------------------------------------------------
// Statevector: 9 wires, 512 amps. amp I = (lane<<3) | r. One wave = one row.
//   wires 0..2 -> bits 0..2 of r (in-register, 8 complex amps/lane)
//   wires 3..8 -> lane bits, remapped so shuffles use the cheapest path:
//     wire:  3    4    5    6    7        8
//     bit:   4    0    1    3    5        2
//     mask:  16   1    2    8    32       4
//     path:  swz  dpp  dpp  dpp  permlane swz
//   DPP quad_perm/row_ror and permlane32_swap are VALU-pipe (no lgkmcnt);
//   only masks 4/16 remain on the LDS pipe (ds_swizzle).
// ---------------------------------------------------------------------------

__host__ __device__ constexpr int bitof(int W) {
  return W == 3 ? 4 : W == 4 ? 0 : W == 5 ? 1 : W == 6 ? 3 : W == 7 ? 5 : 2;
}

template<int CTRL>
__device__ __forceinline__ float dppf(float v) {
  return __int_as_float(__builtin_amdgcn_update_dpp(
      0, __float_as_int(v), CTRL, 0xF, 0xF, false));
}
template<int OFF>
__device__ __forceinline__ float swzf(float v) {
  return __int_as_float(__builtin_amdgcn_ds_swizzle(__float_as_int(v), OFF));
}
__device__ __forceinline__ float xor32f(float v, int lane) {
#if __has_builtin(__builtin_amdgcn_permlane32_swap)
  typedef int i2_t __attribute__((ext_vector_type(2)));
  i2_t r = __builtin_amdgcn_permlane32_swap(__float_as_int(v), __float_as_int(v),
                                            false, false);
  // new vdst = [v_lo | v_lo], new src = [v_hi | v_hi]
  return __int_as_float((lane >= 32) ? r.x : r.y);
#else
  return __shfl_xor(v, 32, 64);
#endif
}

template<int M>
__device__ __forceinline__ float lxor(float v, int lane) {
  if constexpr (M == 1)       return dppf<0xB1>(v);    // quad_perm [1,0,3,2]
  else if constexpr (M == 2)  return dppf<0x4E>(v);    // quad_perm [2,3,0,1]
  else if constexpr (M == 4)  return swzf<0x101F>(v);  // ds_swizzle xor 4
  else if constexpr (M == 8)  return dppf<0x128>(v);   // row_ror:8 == xor 8
  else if constexpr (M == 16) return swzf<0x401F>(v);  // ds_swizzle xor 16
  else                        return xor32f(v, lane);  // permlane32_swap
}

template<int N>
__device__ __forceinline__ void allred(float (&v)[N], int lane) {
#pragma unroll
  for (int q = 0; q < N; ++q) v[q] += lxor<1>(v[q], lane);
#pragma unroll
  for (int q = 0; q < N; ++q) v[q] += lxor<2>(v[q], lane);
#pragma unroll
  for (int q = 0; q < N; ++q) v[q] += lxor<4>(v[q], lane);
#pragma unroll
  for (int q = 0; q < N; ++q) v[q] += lxor<8>(v[q], lane);
#pragma unroll
  for (int q = 0; q < N; ++q) v[q] += lxor<16>(v[q], lane);
#pragma unroll
  for (int q = 0; q < N; ++q) v[q] += lxor<32>(v[q], lane);
}

// RZ: diag(e^{-i t/2}, e^{+i t/2}) — diagonal, zero shuffles.
template<int W>
__device__ __forceinline__ void gate_rz(float (&re)[8], float (&im)[8],
                                        float c, float s, int lane) {
  if constexpr (W < 3) {
#pragma unroll
    for (int r = 0; r < 8; ++r) {
      const float t = ((r >> W) & 1) ? s : -s;
      const float xx = re[r], yy = im[r];
      re[r] = xx * c - yy * t;
      im[r] = yy * c + xx * t;
    }
  } else {
    const float t = ((lane >> bitof(W)) & 1) ? s : -s;
#pragma unroll
    for (int r = 0; r < 8; ++r) {
      const float xx = re[r], yy = im[r];
      re[r] = xx * c - yy * t;
      im[r] = yy * c + xx * t;
    }
  }
}

// RY: [[c, -s], [s, c]]
template<int W>
__device__ __forceinline__ void gate_ry(float (&re)[8], float (&im)[8],
                                        float c, float s, int lane) {
  if constexpr (W < 3) {
#pragma unroll
    for (int r = 0; r < 8; ++r) {
      if (!((r >> W) & 1)) {
        const int r2 = r | (1 << W);
        const float ar = re[r], ai = im[r], br = re[r2], bi = im[r2];
        re[r]  = c * ar - s * br;
        im[r]  = c * ai - s * bi;
        re[r2] = s * ar + c * br;
        im[r2] = s * ai + c * bi;
      }
    }
  } else {
    constexpr int M = 1 << bitof(W);
    const float t = ((lane >> bitof(W)) & 1) ? s : -s;
#pragma unroll
    for (int r = 0; r < 8; ++r) {
      const float ore = lxor<M>(re[r], lane);
      const float oim = lxor<M>(im[r], lane);
      re[r] = c * re[r] + t * ore;
      im[r] = c * im[r] + t * oim;
    }
  }
}

// CNOT(C, T)
template<int C, int T>
__device__ __forceinline__ void gate_cnot(float (&re)[8], float (&im)[8], int lane) {
  if constexpr (C < 3 && T < 3) {          // both local: register permute
#pragma unroll
    for (int r = 0; r < 8; ++r) {
      if (((r >> C) & 1) && !((r >> T) & 1)) {
        const int r2 = r | (1 << T);
        const float tr = re[r], ti = im[r];
        re[r] = re[r2]; im[r] = im[r2];
        re[r2] = tr;    im[r2] = ti;
      }
    }
  } else if constexpr (C < 3) {            // local control, lane target
    constexpr int M = 1 << bitof(T);
#pragma unroll
    for (int r = 0; r < 8; ++r) {
      if ((r >> C) & 1) {
        re[r] = lxor<M>(re[r], lane);
        im[r] = lxor<M>(im[r], lane);
      }
    }
  } else if constexpr (T < 3) {            // lane control, local target: selects
    const bool cc = (lane >> bitof(C)) & 1;
#pragma unroll
    for (int r = 0; r < 8; ++r) {
      if (!((r >> T) & 1)) {
        const int r2 = r | (1 << T);
        const float ar = re[r], ai = im[r], br = re[r2], bi = im[r2];
        re[r]  = cc ? br : ar;  im[r]  = cc ? bi : ai;
        re[r2] = cc ? ar : br;  im[r2] = cc ? ai : bi;
      }
    }
  } else {                                 // lane control, lane target
    constexpr int M = 1 << bitof(T);
    const bool cc = (lane >> bitof(C)) & 1;
#pragma unroll
    for (int r = 0; r < 8; ++r) {
      const float orr = lxor<M>(re[r], lane);
      const float oii = lxor<M>(im[r], lane);
      re[r] = cc ? orr : re[r];
      im[r] = cc ? oii : im[r];
    }
  }
}

__device__ __forceinline__ void cmul(float& dr, float& di,
                                     float ar, float ai, float br, float bi) {
  const float rr = ar * br - ai * bi;
  const float ii = ar * bi + ai * br;
  dr = rr; di = ii;
}

// ---------------------------------------------------------------------------
__global__ void precompute_trig(const float* __restrict__ qw, float* __restrict__ cs) {
  const int i = threadIdx.x;
  if (i < 36) {
    float s, c;
    sincosf(0.5f * qw[i], &s, &c);
    cs[2 * i]     = c;
    cs[2 * i + 1] = s;
  }
}

// ---------------------------------------------------------------------------
// One wave per row. enc+L0 replaced by closed-form product state.
// ---------------------------------------------------------------------------
__global__ __launch_bounds__(256, 4)
void quantum_fused(const float* __restrict__ x,
                   const float* __restrict__ w_in,
                   const float* __restrict__ b_in,
                   const float* __restrict__ gamma,
                   const float* __restrict__ beta,
                   const float* __restrict__ w_out,
                   const float* __restrict__ b_out,
                   const float* __restrict__ cs,
                   float* __restrict__ out) {
  const int lane = threadIdx.x & 63;
  const int wv   = threadIdx.x >> 6;
  const int row  = blockIdx.x * 4 + wv;

  const float4* xv = (const float4*)(x + (size_t)row * DIM);
  float4 xr[3];
#pragma unroll
  for (int k = 0; k < 3; ++k) xr[k] = xv[lane + 64 * k];

  // ---- input projection ----
  float h[8];
#pragma unroll
  for (int q = 0; q < 8; ++q) {
    const float4* wq = (const float4*)(w_in + q * DIM);
    float acc = 0.f;
#pragma unroll
    for (int k = 0; k < 3; ++k) {
      const float4 w4 = wq[lane + 64 * k];
      acc += xr[k].x * w4.x + xr[k].y * w4.y + xr[k].z * w4.z + xr[k].w * w4.w;
    }
    h[q] = acc;
  }
  allred(h, lane);

  // ---- bias + tanh + LayerNorm ----
#pragma unroll
  for (int q = 0; q < 8; ++q) h[q] = tanhf(h[q] + b_in[q]);
  float mu = 0.f;
#pragma unroll
  for (int q = 0; q < 8; ++q) mu += h[q];
  mu *= 0.125f;
  float var = 0.f;
#pragma unroll
  for (int q = 0; q < 8; ++q) { const float d = h[q] - mu; var += d * d; }
  var *= 0.125f;
  const float inv = 1.0f / sqrtf(var + EPSLN);
  float ang[8];
#pragma unroll
  for (int q = 0; q < 8; ++q)
    ang[q] = (h[q] - mu) * inv * gamma[q] + beta[q];

  // ---- product state after enc + layer-0 (all single-qubit) ----
  // psi_i = RZ(w1i)·RX(w0i)·RZ(a)·RX(a)|0>, wire 8 stays |0>.
  float f0r[8], f0i[8], f1r[8], f1i[8];
#pragma unroll
  for (int i = 0; i < 8; ++i) {
    float sa, ca;
    __sincosf(0.5f * ang[i], &sa, &ca);
    const float p0r = ca * ca, p0i = -ca * sa;     // e^{-ia/2} cos(a/2)
    const float p1r = sa * sa, p1i = -sa * ca;     // -i e^{+ia/2} sin(a/2)
    const float c0 = cs[2 * i],        s0 = cs[2 * i + 1];        // RX(w[0,i])
    const float cz = cs[2 * (9 + i)],  sz = cs[2 * (9 + i) + 1];  // RZ(w[1,i])
    const float q0r = c0 * p0r + s0 * p1i, q0i = c0 * p0i - s0 * p1r;
    const float q1r = s0 * p0i + c0 * p1r, q1i = -s0 * p0r + c0 * p1i;
    f0r[i] = cz * q0r + sz * q0i;  f0i[i] = cz * q0i - sz * q0r;
    f1r[i] = cz * q1r - sz * q1i;  f1i[i] = cz * q1i + sz * q1r;
  }

  // local tensor over wires 0..2 -> t[8]
  float tr[8], ti[8];
  tr[0] = f0r[0]; ti[0] = f0i[0];
  tr[1] = f1r[0]; ti[1] = f1i[0];
#pragma unroll
  for (int b = 0; b < 2; ++b) {
    cmul(tr[2 + b], ti[2 + b], tr[b], ti[b], f1r[1], f1i[1]);
    cmul(tr[b],     ti[b],     tr[b], ti[b], f0r[1], f0i[1]);
  }
#pragma unroll
  for (int b = 0; b < 4; ++b) {
    cmul(tr[4 + b], ti[4 + b], tr[b], ti[b], f1r[2], f1i[2]);
    cmul(tr[b],     ti[b],     tr[b], ti[b], f0r[2], f0i[2]);
  }

  // lane factor over wires 3..7 (wire 8 bit -> amplitude is zero)
  float Lr, Li;
  {
    const bool b3 = (lane >> bitof(3)) & 1;
    Lr = b3 ? f1r[3] : f0r[3];
    Li = b3 ? f1i[3] : f0i[3];
#pragma unroll
    for (int i = 4; i < 8; ++i) {
      const bool b = (lane >> bitof(i)) & 1;
      const float gr = b ? f1r[i] : f0r[i];
      const float gi = b ? f1i[i] : f0i[i];
      cmul(Lr, Li, Lr, Li, gr, gi);
    }
    if ((lane >> bitof(8)) & 1) { Lr = 0.f; Li = 0.f; }
  }

  float re[8], im[8];
#pragma unroll
  for (int r = 0; r < 8; ++r) {
    re[r] = tr[r] * Lr - ti[r] * Li;
    im[r] = tr[r] * Li + ti[r] * Lr;
  }

  // ---- layers 1..3 ----
#define LSTEP(l, i, j) { gate_cnot<i, j>(re, im, lane);                        \
                         const float c_ = cs[2*((l)*9+(i))];                   \
                         const float s_ = cs[2*((l)*9+(i))+1];                 \
                         gate_ry<i>(re, im, c_, s_, lane);                     \
                         gate_rz<i>(re, im, c_, s_, lane); }
#define LAYER(l)                                                               \
  LSTEP(l,0,1) LSTEP(l,1,2) LSTEP(l,2,3) LSTEP(l,3,4)                          \
  LSTEP(l,4,5) LSTEP(l,5,6) LSTEP(l,6,7) LSTEP(l,7,0)                          \
  { gate_cnot<7, 8>(re, im, lane);                                             \
    gate_ry<8>(re, im, cs[2*((l)*9+8)], cs[2*((l)*9+8)+1], lane); }
  LAYER(1) LAYER(2) LAYER(3)
#undef LAYER
#undef LSTEP

  // ---- measurement ----
  float p[8];
#pragma unroll
  for (int r = 0; r < 8; ++r) p[r] = re[r] * re[r] + im[r] * im[r];
  float ptot = 0.f;
#pragma unroll
  for (int r = 0; r < 8; ++r) ptot += p[r];
  float z[8];
#pragma unroll
  for (int i = 0; i < 3; ++i) {
    float acc = 0.f;
#pragma unroll
    for (int r = 0; r < 8; ++r) acc += ((r >> i) & 1) ? -p[r] : p[r];
    z[i] = acc;
  }
#pragma unroll
  for (int i = 3; i < 8; ++i)
    z[i] = ((lane >> bitof(i)) & 1) ? -ptot : ptot;
  allred(z, lane);

  // ---- output projection + residual ----
  float* orow = out + (size_t)row * DIM;
  float4* ov = (float4*)orow;
  const float4* bv = (const float4*)b_out;
#pragma unroll
  for (int k = 0; k < 3; ++k) {
    const int j4 = lane + 64 * k;
    const float4 b4 = bv[j4];
    const float4* wo = (const float4*)(w_out + (size_t)j4 * 32);
    const float4 r0a = wo[0], r0b = wo[1];
    const float4 r1a = wo[2], r1b = wo[3];
    const float4 r2a = wo[4], r2b = wo[5];
    const float4 r3a = wo[6], r3b = wo[7];
    float4 o;
    o.x = xr[k].x + b4.x + z[0]*r0a.x + z[1]*r0a.y + z[2]*r0a.z + z[3]*r0a.w
                        + z[4]*r0b.x + z[5]*r0b.y + z[6]*r0b.z + z[7]*r0b.w;
    o.y = xr[k].y + b4.y + z[0]*r1a.x + z[1]*r1a.y + z[2]*r1a.z + z[3]*r1a.w
                        + z[4]*r1b.x + z[5]*r1b.y + z[6]*r1b.z + z[7]*r1b.w;
    o.z = xr[k].z + b4.z + z[0]*r2a.x + z[1]*r2a.y + z[2]*r2a.z + z[3]*r2a.w
                        + z[4]*r2b.x + z[5]*r2b.y + z[6]*r2b.z + z[7]*r2b.w;
    o.w = xr[k].w + b4.w + z[0]*r3a.x + z[1]*r3a.y + z[2]*r3a.z + z[3]*r3a.w
                        + z[4]*r3b.x + z[5]*r3b.y + z[6]*r3b.z + z[7]*r3b.w;
    ov[j4] = o;
  }
}

extern "C" void kernel_launch(void* const* d_in, const int* in_sizes, int n_in,
                              void* d_out, int out_size, void* d_ws, size_t ws_size,
                              hipStream_t stream) {
  const float* x     = (const float*)d_in[0];
  const float* w_in  = (const float*)d_in[1];
  const float* b_in  = (const float*)d_in[2];
  const float* gamma = (const float*)d_in[3];
  const float* beta  = (const float*)d_in[4];
  const float* q_w   = (const float*)d_in[5];
  const float* w_out = (const float*)d_in[6];
  const float* b_out = (const float*)d_in[7];
  float* outp = (float*)d_out;
  float* cs   = (float*)d_ws;   // 72 floats: (cos, sin) of q_w/2

  hipLaunchKernelGGL(precompute_trig, dim3(1), dim3(64), 0, stream, q_w, cs);
  hipLaunchKernelGGL(quantum_fused, dim3(BATCH / 4), dim3(256), 0, stream,
                     x, w_in, b_in, gamma, beta, w_out, b_out, cs, outp);
}